// Round 11
// baseline (239.146 us; speedup 1.0000x reference)
//
#include <hip/hip_runtime.h>
#include <hip/hip_bf16.h>

#define BATCH 16
#define CDIM  512
#define SEQ   1024
#define HEADS 8
#define DHEAD 64
#define N3    1536      // 3 * HEADS * DHEAD
#define ATTN_SCALE 0.125f

typedef unsigned short ushort_t;
typedef __attribute__((ext_vector_type(8))) short short8;   // 8 bf16 (4 VGPRs)
typedef __attribute__((ext_vector_type(4))) float f32x4;

// fp32 -> bf16 bits, round-to-nearest-even
__device__ __forceinline__ ushort_t f2bf(float f) {
    unsigned u = __float_as_uint(f);
    u += 0x7fffu + ((u >> 16) & 1u);
    return (ushort_t)(u >> 16);
}
// fp32 -> bf16 bits, truncation (1 op; P self-normalizes through l)
__device__ __forceinline__ unsigned bfu_trunc(float f) {
    return __float_as_uint(f) >> 16;
}
// async global->LDS, 16B per lane; per-lane global addr, LDS dest = uniform base + lane*16
__device__ __forceinline__ void async16(const void* g, void* l) {
    __builtin_amdgcn_global_load_lds(
        (const __attribute__((address_space(1))) unsigned int*)g,
        (__attribute__((address_space(3))) unsigned int*)l, 16, 0, 0);
}

// ---------------------------------------------------------------------------
// Kernel 0: transpose + fp32->bf16 convert.  in[R][C] fp32 -> out[C][R] bf16.
//   Grid: (C/64, R/64, batch); 256 threads; 64x64 LDS tile.
// ---------------------------------------------------------------------------
__global__ __launch_bounds__(256) void transpose_bf16_kernel(
    const float* __restrict__ in, ushort_t* __restrict__ out, int R, int C)
{
    __shared__ float t[64][65];
    const int r0 = blockIdx.y * 64, c0 = blockIdx.x * 64;
    const float* inb = in + (size_t)blockIdx.z * R * C;
    ushort_t* outb = out + (size_t)blockIdx.z * R * C;
    const int tid = threadIdx.x;
#pragma unroll
    for (int i = 0; i < 16; ++i) {
        int idx = tid + i * 256;
        int r = idx >> 6, c = idx & 63;
        t[r][c] = inb[(size_t)(r0 + r) * C + c0 + c];
    }
    __syncthreads();
#pragma unroll
    for (int i = 0; i < 8; ++i) {
        int idx = tid + i * 256;       // 0..2047 uints
        int c = idx >> 5, rp = idx & 31;
        unsigned lo = f2bf(t[rp * 2][c]);
        unsigned hi = f2bf(t[rp * 2 + 1][c]);
        *(unsigned*)&outb[(size_t)(c0 + c) * R + r0 + rp * 2] = lo | (hi << 16);
    }
}

// ---------------------------------------------------------------------------
// Kernel 1: QKV GEMM (MFMA), BK=64 double-buffered (8 iters, one barrier
//   each; 32 KB in flight per block) + XCD swizzle (all 12 n-blocks of one
//   m-tile on the same XCD -> A-tile L2 locality).
//   C[m][n] = xt[m][:] . WpT[n][:] + bias.  128x128 tile, 2x2 waves,
//   4x4 frags/wave.  Epilogue: q pre-scaled; split q/k [bh][s][d], vT [bh][d][s].
//   Grid: (12, 128); 256 threads; 64 KB LDS.
// ---------------------------------------------------------------------------
__global__ __launch_bounds__(256) void qkv_gemm_kernel(
    const ushort_t* __restrict__ xt, const ushort_t* __restrict__ WpT,
    const float* __restrict__ bp,
    ushort_t* __restrict__ q_buf, ushort_t* __restrict__ k_buf,
    ushort_t* __restrict__ vT)
{
    __shared__ alignas(16) ushort_t Asub[2][16 * 512];   // 2 x 16 KB
    __shared__ alignas(16) ushort_t Bsub[2][16 * 512];   // 2 x 16 KB

    const int tid = threadIdx.x, w = tid >> 6, lane = tid & 63;
    const int quad = lane >> 4, col = lane & 15;
    const int wm = w >> 1, wn = w & 1;

    // XCD swizzle: lin%8 = XCD (heuristic). Group all 12 n-tiles of one
    // m-tile onto one XCD: m_t = (r/12)*8 + xcd, n_t = r%12, r = lin>>3.
    const int lin = blockIdx.x + 12 * blockIdx.y;   // 0..1535
    const int xcd = lin & 7;
    const int rr  = lin >> 3;                       // 0..191
    const int n0  = (rr % 12) * 128;
    const int m0  = ((rr / 12) * 8 + xcd) * 128;

    f32x4 acc[4][4];
#pragma unroll
    for (int i = 0; i < 4; ++i)
#pragma unroll
        for (int j = 0; j < 4; ++j) acc[i][j] = (f32x4){0.f, 0.f, 0.f, 0.f};

    // wave w stages A/B rows m16(n16) = w*2+{0,1}, both k32-halves
    const ushort_t* Ag0 = xt  + (size_t)(m0 + (w * 2 + 0) * 16 + col) * 512 + quad * 8;
    const ushort_t* Ag1 = xt  + (size_t)(m0 + (w * 2 + 1) * 16 + col) * 512 + quad * 8;
    const ushort_t* Bg0 = WpT + (size_t)(n0 + (w * 2 + 0) * 16 + col) * 512 + quad * 8;
    const ushort_t* Bg1 = WpT + (size_t)(n0 + (w * 2 + 1) * 16 + col) * 512 + quad * 8;

#define QKV_STAGE(buf, ko)                                                      \
    do {                                                                        \
        async16(Ag0 + (ko),      &Asub[buf][((w * 2 + 0) * 2 + 0) * 512]);      \
        async16(Ag0 + (ko) + 32, &Asub[buf][((w * 2 + 0) * 2 + 1) * 512]);      \
        async16(Ag1 + (ko),      &Asub[buf][((w * 2 + 1) * 2 + 0) * 512]);      \
        async16(Ag1 + (ko) + 32, &Asub[buf][((w * 2 + 1) * 2 + 1) * 512]);      \
        async16(Bg0 + (ko),      &Bsub[buf][((w * 2 + 0) * 2 + 0) * 512]);      \
        async16(Bg0 + (ko) + 32, &Bsub[buf][((w * 2 + 0) * 2 + 1) * 512]);      \
        async16(Bg1 + (ko),      &Bsub[buf][((w * 2 + 1) * 2 + 0) * 512]);      \
        async16(Bg1 + (ko) + 32, &Bsub[buf][((w * 2 + 1) * 2 + 1) * 512]);      \
    } while (0)

    QKV_STAGE(0, 0);
    for (int it = 0; it < 8; ++it) {
        const int cur = it & 1;
        __syncthreads();                 // buf[cur] staged; buf[cur^1] readers done
        if (it < 7) QKV_STAGE(cur ^ 1, (it + 1) * 64);

#pragma unroll
        for (int kh = 0; kh < 2; ++kh) {
            short8 af[4], bfr[4];
#pragma unroll
            for (int i = 0; i < 4; ++i)
                af[i] = *(const short8*)&Asub[cur][((wm * 4 + i) * 2 + kh) * 512 + lane * 8];
#pragma unroll
            for (int j = 0; j < 4; ++j)
                bfr[j] = *(const short8*)&Bsub[cur][((wn * 4 + j) * 2 + kh) * 512 + lane * 8];
#pragma unroll
            for (int i = 0; i < 4; ++i)
#pragma unroll
                for (int j = 0; j < 4; ++j)
                    acc[i][j] = __builtin_amdgcn_mfma_f32_16x16x32_bf16(af[i], bfr[j], acc[i][j], 0, 0, 0);
        }
    }
#undef QKV_STAGE

    // ---- epilogue: split q/k/v; q pre-scaled by ATTN_SCALE ----
    const int b = m0 >> 10, s0 = m0 & 1023;
    const size_t b8 = (size_t)b * HEADS;
#pragma unroll
    for (int j = 0; j < 4; ++j) {
        int nb = n0 + wn * 64 + j * 16;               // frag n base (wave-uniform)
        int h = nb / 192, rem = nb % 192;
        int type = rem >> 6, dbase = rem & 63;        // uniform per frag
        float bias = bp[nb + col];
        float scl = (type == 0) ? ATTN_SCALE : 1.0f;
        size_t bh = b8 + h;
#pragma unroll
        for (int i = 0; i < 4; ++i) {
            int sb = s0 + wm * 64 + i * 16 + quad * 4;    // s for r=0
            f32x4 v = acc[i][j];
            if (type == 2) {
                unsigned lo = (unsigned)f2bf(v[0] + bias) | ((unsigned)f2bf(v[1] + bias) << 16);
                unsigned hi = (unsigned)f2bf(v[2] + bias) | ((unsigned)f2bf(v[3] + bias) << 16);
                uint2 pk; pk.x = lo; pk.y = hi;
                *(uint2*)&vT[(bh * DHEAD + dbase + col) * SEQ + sb] = pk;
            } else {
                ushort_t* dst = (type == 0) ? q_buf : k_buf;
#pragma unroll
                for (int r = 0; r < 4; ++r)
                    dst[(bh * SEQ + sb + r) * DHEAD + dbase + col] = f2bf((v[r] + bias) * scl);
            }
        }
    }
}

// ---------------------------------------------------------------------------
// Kernel 2: MFMA flash attention (unchanged from R10 — passing, dbuf'd).
//   Grid: (bh=128, qtile=8); 256 threads; 48 KB LDS.
// ---------------------------------------------------------------------------
__global__ __launch_bounds__(256) void attn_kernel(
    const ushort_t* __restrict__ q_buf, const ushort_t* __restrict__ k_buf,
    const ushort_t* __restrict__ vT, ushort_t* __restrict__ resb)
{
    __shared__ alignas(16) ushort_t Kf[2][8 * 512];   // ping-pong, 16 KB
    __shared__ alignas(16) ushort_t Vf[2][8 * 512];   // ping-pong, 16 KB
    __shared__ alignas(16) ushort_t Pf[8 * 1024];     // 16 KB: 4 waves x 2 groups

    const int tid  = threadIdx.x;
    const int w    = tid >> 6;
    const int lane = tid & 63;
    const int quad = lane >> 4;
    const int col  = lane & 15;

    const int bhid = blockIdx.x;          // 0..127
    const int b = bhid >> 3, h = bhid & 7;
    const int q0 = blockIdx.y * 128;
    const size_t bh = (size_t)b * HEADS + h;

    // Q B-frags for 2 groups (pre-scaled by ATTN_SCALE in qkv_gemm)
    const ushort_t* qp = q_buf + ((bh * SEQ) + q0 + w * 32 + col) * DHEAD + quad * 8;
    short8 qf0[2], qf1[2];
    qf0[0] = *(const short8*)(qp);
    qf1[0] = *(const short8*)(qp + 32);
    qf0[1] = *(const short8*)(qp + 16 * DHEAD);
    qf1[1] = *(const short8*)(qp + 16 * DHEAD + 32);

    short8 ones;   // bf16 1.0 splat for row-sum MFMA
#pragma unroll
    for (int i = 0; i < 8; ++i) ones[i] = (short)0x3F80;

    f32x4 O[2][4];
#pragma unroll
    for (int g = 0; g < 2; ++g)
#pragma unroll
        for (int i = 0; i < 4; ++i) O[g][i] = (f32x4){0.f, 0.f, 0.f, 0.f};
    f32x4 L[2];
    L[0] = (f32x4){0.f, 0.f, 0.f, 0.f};
    L[1] = (f32x4){0.f, 0.f, 0.f, 0.f};

    // staging pointers (wave w stages K t16=w, V d16=w)
    const ushort_t* ka = k_buf + (bh * SEQ + w * 16 + col) * DHEAD + quad * 8;
    const ushort_t* va = vT + (bh * DHEAD + w * 16 + col) * SEQ + quad * 8;

    // P write offset: off = (t16>>1)*512 + ((t16*2+(quad>>1))&3)*128 + col*8 + (quad&1)*4
    const int poff_base = col * 8 + (quad & 1) * 4;
    const int qh = quad >> 1;

    // prologue: stage t-iter 0 into buffer 0
    async16(ka,      &Kf[0][(w * 2 + 0) * 512]);
    async16(ka + 32, &Kf[0][(w * 2 + 1) * 512]);
    async16(va,      &Vf[0][(w * 2 + 0) * 512]);
    async16(va + 32, &Vf[0][(w * 2 + 1) * 512]);
    ka += 64 * DHEAD;
    va += 64;

    for (int it = 0; it < 16; ++it) {
        const int cur = it & 1;
        const ushort_t* kc = Kf[cur];
        const ushort_t* vc = Vf[cur];
        __syncthreads();   // buf[cur] staged; prior readers of buf[cur^1] done
        if (it < 15) {
            ushort_t* kn = Kf[cur ^ 1];
            ushort_t* vn = Vf[cur ^ 1];
            async16(ka,      &kn[(w * 2 + 0) * 512]);
            async16(ka + 32, &kn[(w * 2 + 1) * 512]);
            async16(va,      &vn[(w * 2 + 0) * 512]);
            async16(va + 32, &vn[(w * 2 + 1) * 512]);
            ka += 64 * DHEAD;
            va += 64;
        }

        // ---- S^T = K Q^T (Q pre-scaled); K frags shared by both groups ----
        f32x4 S[2][4];
#pragma unroll
        for (int t16 = 0; t16 < 4; ++t16) {
            const short8 k0 = *(const short8*)&kc[(t16 * 2 + 0) * 512 + lane * 8];
            const short8 k1 = *(const short8*)&kc[(t16 * 2 + 1) * 512 + lane * 8];
#pragma unroll
            for (int g = 0; g < 2; ++g) {
                f32x4 a = (f32x4){0.f, 0.f, 0.f, 0.f};
                a = __builtin_amdgcn_mfma_f32_16x16x32_bf16(k0, qf0[g], a, 0, 0, 0);
                a = __builtin_amdgcn_mfma_f32_16x16x32_bf16(k1, qf1[g], a, 0, 0, 0);
                S[g][t16] = a;
            }
        }

        // ---- P = exp(S) -> A-layout LDS (1 ds_write_b64 per (g,t16)) ----
#pragma unroll
        for (int g = 0; g < 2; ++g) {
            ushort_t* pg = &Pf[(w * 2 + g) * 1024];
#pragma unroll
            for (int t16 = 0; t16 < 4; ++t16) {
                uint2 pk;
                pk.x = bfu_trunc(__expf(S[g][t16][0])) | (bfu_trunc(__expf(S[g][t16][1])) << 16);
                pk.y = bfu_trunc(__expf(S[g][t16][2])) | (bfu_trunc(__expf(S[g][t16][3])) << 16);
                int off = (t16 >> 1) * 512 + (((t16 * 2) + qh) & 3) * 128 + poff_base;
                *(uint2*)&pg[off] = pk;    // ds_write_b64
            }
        }
        // own-wave LDS RAW: ordered by lgkmcnt, no barrier needed
        short8 pf[2][2];
#pragma unroll
        for (int g = 0; g < 2; ++g) {
            const ushort_t* pg = &Pf[(w * 2 + g) * 1024];
            pf[g][0] = *(const short8*)&pg[lane * 8];
            pf[g][1] = *(const short8*)&pg[512 + lane * 8];
        }

        // ---- O += P V ; V frags shared by both groups ----
#pragma unroll
        for (int d16 = 0; d16 < 4; ++d16) {
            const short8 v0 = *(const short8*)&vc[(d16 * 2 + 0) * 512 + lane * 8];
            const short8 v1 = *(const short8*)&vc[(d16 * 2 + 1) * 512 + lane * 8];
#pragma unroll
            for (int g = 0; g < 2; ++g) {
                O[g][d16] = __builtin_amdgcn_mfma_f32_16x16x32_bf16(pf[g][0], v0, O[g][d16], 0, 0, 0);
                O[g][d16] = __builtin_amdgcn_mfma_f32_16x16x32_bf16(pf[g][1], v1, O[g][d16], 0, 0, 0);
            }
        }
#pragma unroll
        for (int g = 0; g < 2; ++g) {
            L[g] = __builtin_amdgcn_mfma_f32_16x16x32_bf16(pf[g][0], ones, L[g], 0, 0, 0);
            L[g] = __builtin_amdgcn_mfma_f32_16x16x32_bf16(pf[g][1], ones, L[g], 0, 0, 0);
        }
    }

    // ---- epilogue: O / L -> res[m][h*64+d] ----
#pragma unroll
    for (int g = 0; g < 2; ++g)
#pragma unroll
        for (int r = 0; r < 4; ++r) {
            float inv = 1.f / L[g][r];
            int qg = q0 + w * 32 + g * 16 + quad * 4 + r;
            size_t base_o = ((size_t)b * SEQ + qg) * (HEADS * DHEAD) + h * DHEAD + col;
#pragma unroll
            for (int d16 = 0; d16 < 4; ++d16)
                resb[base_o + d16 * 16] = f2bf(O[g][d16][r] * inv);
        }
}

// ---------------------------------------------------------------------------
// Kernel 3: out GEMM (MFMA), BK=64 double-buffered + XCD swizzle.
//   out[b][n][s] = res[m][:].WoT[n][:] + bo[n] + x.  Grid: (4, 128).
// ---------------------------------------------------------------------------
__global__ __launch_bounds__(256) void out_gemm_kernel(
    const ushort_t* __restrict__ res, const ushort_t* __restrict__ WoT,
    const float* __restrict__ bo, const float* __restrict__ x,
    float* __restrict__ out)
{
    __shared__ alignas(16) ushort_t Asub[2][16 * 512];
    __shared__ alignas(16) ushort_t Bsub[2][16 * 512];

    const int tid = threadIdx.x, w = tid >> 6, lane = tid & 63;
    const int quad = lane >> 4, col = lane & 15;
    const int wm = w >> 1, wn = w & 1;

    // XCD swizzle: group all 4 n-tiles of one m-tile onto one XCD
    const int lin = blockIdx.x + 4 * blockIdx.y;    // 0..511
    const int xcd = lin & 7;
    const int rr  = lin >> 3;                       // 0..63
    const int n0  = (rr & 3) * 128;
    const int m0  = ((rr >> 2) * 8 + xcd) * 128;

    f32x4 acc[4][4];
#pragma unroll
    for (int i = 0; i < 4; ++i)
#pragma unroll
        for (int j = 0; j < 4; ++j) acc[i][j] = (f32x4){0.f, 0.f, 0.f, 0.f};

    const ushort_t* Ag0 = res + (size_t)(m0 + (w * 2 + 0) * 16 + col) * 512 + quad * 8;
    const ushort_t* Ag1 = res + (size_t)(m0 + (w * 2 + 1) * 16 + col) * 512 + quad * 8;
    const ushort_t* Bg0 = WoT + (size_t)(n0 + (w * 2 + 0) * 16 + col) * 512 + quad * 8;
    const ushort_t* Bg1 = WoT + (size_t)(n0 + (w * 2 + 1) * 16 + col) * 512 + quad * 8;

#define OUT_STAGE(buf, ko)                                                      \
    do {                                                                        \
        async16(Ag0 + (ko),      &Asub[buf][((w * 2 + 0) * 2 + 0) * 512]);      \
        async16(Ag0 + (ko) + 32, &Asub[buf][((w * 2 + 0) * 2 + 1) * 512]);      \
        async16(Ag1 + (ko),      &Asub[buf][((w * 2 + 1) * 2 + 0) * 512]);      \
        async16(Ag1 + (ko) + 32, &Asub[buf][((w * 2 + 1) * 2 + 1) * 512]);      \
        async16(Bg0 + (ko),      &Bsub[buf][((w * 2 + 0) * 2 + 0) * 512]);      \
        async16(Bg0 + (ko) + 32, &Bsub[buf][((w * 2 + 0) * 2 + 1) * 512]);      \
        async16(Bg1 + (ko),      &Bsub[buf][((w * 2 + 1) * 2 + 0) * 512]);      \
        async16(Bg1 + (ko) + 32, &Bsub[buf][((w * 2 + 1) * 2 + 1) * 512]);      \
    } while (0)

    OUT_STAGE(0, 0);
    for (int it = 0; it < 8; ++it) {
        const int cur = it & 1;
        __syncthreads();
        if (it < 7) OUT_STAGE(cur ^ 1, (it + 1) * 64);

#pragma unroll
        for (int kh = 0; kh < 2; ++kh) {
            short8 af[4], bfr[4];
#pragma unroll
            for (int i = 0; i < 4; ++i)
                af[i] = *(const short8*)&Asub[cur][((wm * 4 + i) * 2 + kh) * 512 + lane * 8];
#pragma unroll
            for (int j = 0; j < 4; ++j)
                bfr[j] = *(const short8*)&Bsub[cur][((wn * 4 + j) * 2 + kh) * 512 + lane * 8];
#pragma unroll
            for (int i = 0; i < 4; ++i)
#pragma unroll
                for (int j = 0; j < 4; ++j)
                    acc[i][j] = __builtin_amdgcn_mfma_f32_16x16x32_bf16(af[i], bfr[j], acc[i][j], 0, 0, 0);
        }
    }
#undef OUT_STAGE

    const int b = m0 >> 10, s0 = m0 & 1023;
#pragma unroll
    for (int j = 0; j < 4; ++j) {
        int n = n0 + wn * 64 + j * 16 + col;
        float bias = bo[n];
#pragma unroll
        for (int i = 0; i < 4; ++i) {
            int sb = s0 + wm * 64 + i * 16 + quad * 4;
            size_t o = ((size_t)b * CDIM + n) * SEQ + sb;
            float4 xr = *(const float4*)&x[o];
            f32x4 v = acc[i][j];
            float4 ov;
            ov.x = v[0] + bias + xr.x;
            ov.y = v[1] + bias + xr.y;
            ov.z = v[2] + bias + xr.z;
            ov.w = v[3] + bias + xr.w;
            *(float4*)&out[o] = ov;
        }
    }
}

// ---------------------------------------------------------------------------
extern "C" void kernel_launch(void* const* d_in, const int* in_sizes, int n_in,
                              void* d_out, int out_size, void* d_ws, size_t ws_size,
                              hipStream_t stream) {
    const float* x  = (const float*)d_in[0];   // (16, 512, 32, 32) fp32
    const float* Wp = (const float*)d_in[1];   // (512, 1536) fp32
    const float* bp = (const float*)d_in[2];   // (1536,) fp32
    const float* Wo = (const float*)d_in[3];   // (512, 512) fp32
    const float* bo = (const float*)d_in[4];   // (512,) fp32
    float* out = (float*)d_out;                // (16, 512, 32, 32) fp32

    // ws layout (ushort units), total ~82 MB
    ushort_t* xt    = (ushort_t*)d_ws;               // [m=16384][k=512]
    ushort_t* WpT   = xt    + (size_t)8388608;       // [n=1536][k=512]
    ushort_t* WoT   = WpT   + (size_t)786432;        // [n=512][k=512]
    ushort_t* q_buf = WoT   + (size_t)262144;        // [bh][s][d]
    ushort_t* k_buf = q_buf + (size_t)8388608;
    ushort_t* vTb   = k_buf + (size_t)8388608;       // [bh][d][s]
    ushort_t* resb  = vTb   + (size_t)8388608;       // [m][512]

    transpose_bf16_kernel<<<dim3(16, 8, 16), 256, 0, stream>>>(x,  xt,  512, 1024);
    transpose_bf16_kernel<<<dim3(24, 8, 1),  256, 0, stream>>>(Wp, WpT, 512, 1536);
    transpose_bf16_kernel<<<dim3(8, 8, 1),   256, 0, stream>>>(Wo, WoT, 512, 512);
    qkv_gemm_kernel<<<dim3(12, 128), 256, 0, stream>>>(xt, WpT, bp, q_buf, k_buf, vTb);
    attn_kernel<<<dim3(128, 8), 256, 0, stream>>>(q_buf, k_buf, vTb, resb);
    out_gemm_kernel<<<dim3(4, 128), 256, 0, stream>>>(resb, WoT, bo, x, out);
}

// Round 12
// 202.776 us; speedup vs baseline: 1.1794x; 1.1794x over previous
//
#include <hip/hip_runtime.h>
#include <hip/hip_bf16.h>

#define BATCH 16
#define CDIM  512
#define SEQ   1024
#define HEADS 8
#define DHEAD 64
#define N3    1536      // 3 * HEADS * DHEAD
#define ATTN_SCALE 0.125f

typedef unsigned short ushort_t;
typedef __attribute__((ext_vector_type(8))) short short8;   // 8 bf16 (4 VGPRs)
typedef __attribute__((ext_vector_type(4))) float f32x4;

// fp32 -> bf16 bits, round-to-nearest-even
__device__ __forceinline__ unsigned f2bf(float f) {
    unsigned u = __float_as_uint(f);
    u += 0x7fffu + ((u >> 16) & 1u);
    return u >> 16;
}
// fp32 -> bf16 bits, truncation (1 op; P self-normalizes through l)
__device__ __forceinline__ unsigned bfu_trunc(float f) {
    return __float_as_uint(f) >> 16;
}
// async global->LDS, 16B/lane. Global side: uniform base + lane*16 must be the
// caller's intent -> we pass per-lane ptr already offset by lane*8 ushorts so
// the wave covers 1 KB CONTIGUOUS global memory (1 transaction, not 64).
__device__ __forceinline__ void async16(const void* g, void* l) {
    __builtin_amdgcn_global_load_lds(
        (const __attribute__((address_space(1))) unsigned int*)g,
        (__attribute__((address_space(3))) unsigned int*)l, 16, 0, 0);
}

// ---------------------------------------------------------------------------
// Blocked fragment-order layout for GEMM staging (all staged operands):
//   element (m, k):  mt=m>>7, mr=m&127, m16=mr>>4, col=mr&15,
//                    it=k>>5, q=(k>>3)&3, j=k&7
//   off = ((mt*16+it)*8 + m16)*512 + (q*16+col)*8 + j
// One (mt,it,m16) chunk = 512 ushorts = 1 KB contiguous = one async16/wave.
// ---------------------------------------------------------------------------

// Kernel 0: transpose + bf16 + blockify.  in[512][C] fp32 (k-major), m = z*C+c.
//   Grid: (C/64, 8, batches); 256 threads.
__global__ __launch_bounds__(256) void blockify_kernel(
    const float* __restrict__ in, ushort_t* __restrict__ out, int C)
{
    __shared__ float t[64][65];
    const int k0 = blockIdx.y * 64, c0 = blockIdx.x * 64;
    const float* inb = in + (size_t)blockIdx.z * 512 * C;
    const int tid = threadIdx.x;
#pragma unroll
    for (int i = 0; i < 16; ++i) {
        int idx = tid + i * 256;
        int r = idx >> 6, c = idx & 63;
        t[r][c] = inb[(size_t)(k0 + r) * C + c0 + c];
    }
    __syncthreads();
    const size_t mbase = (size_t)blockIdx.z * C + c0;
    const int ml = tid & 63;
#pragma unroll
    for (int i = 0; i < 2; ++i) {
        int oct = (tid >> 6) + i * 4;          // k-octet 0..7
        size_t m = mbase + ml;
        int mt = (int)(m >> 7), mr = (int)(m & 127);
        int m16 = mr >> 4, col = mr & 15;
        int k = k0 + oct * 8;
        int it = k >> 5, q = (k >> 3) & 3;
        uint4 pk;
        pk.x = f2bf(t[oct * 8 + 0][ml]) | (f2bf(t[oct * 8 + 1][ml]) << 16);
        pk.y = f2bf(t[oct * 8 + 2][ml]) | (f2bf(t[oct * 8 + 3][ml]) << 16);
        pk.z = f2bf(t[oct * 8 + 4][ml]) | (f2bf(t[oct * 8 + 5][ml]) << 16);
        pk.w = f2bf(t[oct * 8 + 6][ml]) | (f2bf(t[oct * 8 + 7][ml]) << 16);
        size_t off = ((size_t)(mt * 16 + it) * 8 + m16) * 512 + (q * 16 + col) * 8;
        *(uint4*)&out[off] = pk;
    }
}

// ---------------------------------------------------------------------------
// Kernel 1: QKV GEMM (MFMA), BK=32 dbuf, blocked staging (contiguous 1KB
//   async16), XCD swizzle.  Epilogue: q row-major (pre-scaled), k/v written in
//   attn's blocked fragment-stage order.  Grid: (12, 128); 256 thr; 32 KB LDS.
// ---------------------------------------------------------------------------
__global__ __launch_bounds__(256) void qkv_gemm_kernel(
    const ushort_t* __restrict__ xtb, const ushort_t* __restrict__ WpTb,
    const float* __restrict__ bp,
    ushort_t* __restrict__ q_buf, ushort_t* __restrict__ kb,
    ushort_t* __restrict__ vb)
{
    __shared__ alignas(16) ushort_t Asub[2][8 * 512];   // 2 x 8 KB
    __shared__ alignas(16) ushort_t Bsub[2][8 * 512];   // 2 x 8 KB

    const int tid = threadIdx.x, w = tid >> 6, lane = tid & 63;
    const int quad = lane >> 4, col = lane & 15;
    const int wm = w >> 1, wn = w & 1;

    // XCD swizzle: all 12 n-tiles of one m-tile on one XCD
    const int lin = blockIdx.x + 12 * blockIdx.y;   // 0..1535
    const int xcd = lin & 7;
    const int rr  = lin >> 3;
    const int n0  = (rr % 12) * 128;
    const int m0  = ((rr / 12) * 8 + xcd) * 128;

    f32x4 acc[4][4];
#pragma unroll
    for (int i = 0; i < 4; ++i)
#pragma unroll
        for (int j = 0; j < 4; ++j) acc[i][j] = (f32x4){0.f, 0.f, 0.f, 0.f};

    // contiguous-chunk staging pointers (global side: +lane*8 ushorts)
    const ushort_t* Ab = xtb  + (size_t)(m0 >> 7) * 65536 + (w * 2) * 512 + lane * 8;
    const ushort_t* Bb = WpTb + (size_t)(n0 >> 7) * 65536 + (w * 2) * 512 + lane * 8;

#define QKV_STAGE(buf, it)                                        \
    do {                                                          \
        async16(Ab + (it) * 4096,       &Asub[buf][(w * 2 + 0) * 512]); \
        async16(Ab + (it) * 4096 + 512, &Asub[buf][(w * 2 + 1) * 512]); \
        async16(Bb + (it) * 4096,       &Bsub[buf][(w * 2 + 0) * 512]); \
        async16(Bb + (it) * 4096 + 512, &Bsub[buf][(w * 2 + 1) * 512]); \
    } while (0)

    QKV_STAGE(0, 0);
    for (int it = 0; it < 16; ++it) {
        const int cur = it & 1;
        __syncthreads();                 // buf[cur] staged; buf[cur^1] readers done
        if (it < 15) QKV_STAGE(cur ^ 1, it + 1);

        short8 af[4], bfr[4];
#pragma unroll
        for (int i = 0; i < 4; ++i) af[i]  = *(const short8*)&Asub[cur][(wm * 4 + i) * 512 + lane * 8];
#pragma unroll
        for (int j = 0; j < 4; ++j) bfr[j] = *(const short8*)&Bsub[cur][(wn * 4 + j) * 512 + lane * 8];
#pragma unroll
        for (int i = 0; i < 4; ++i)
#pragma unroll
            for (int j = 0; j < 4; ++j)
                acc[i][j] = __builtin_amdgcn_mfma_f32_16x16x32_bf16(af[i], bfr[j], acc[i][j], 0, 0, 0);
    }
#undef QKV_STAGE

    // ---- epilogue: split q/k/v; q pre-scaled by ATTN_SCALE ----
    const int b = m0 >> 10, s0 = m0 & 1023;
    const size_t b8 = (size_t)b * HEADS;
#pragma unroll
    for (int j = 0; j < 4; ++j) {
        int nb = n0 + wn * 64 + j * 16;               // frag n base (wave-uniform)
        int h = nb / 192, rem = nb % 192;
        int type = rem >> 6, dbase = rem & 63;        // uniform per frag
        float bias = bp[nb + col];
        size_t bh = b8 + h;
        int d = dbase + col;
#pragma unroll
        for (int i = 0; i < 4; ++i) {
            int sb = s0 + wm * 64 + i * 16 + quad * 4;    // s for r=0
            f32x4 v = acc[i][j];
            if (type == 2) {
                // vb blocked: elem (bh,d,t): it=t>>6, sub=(d>>4)*2+((t>>5)&1),
                //   off = ((bh*16+it)*8+sub)*512 + (((t>>3)&3)*16 + (d&15))*8 + (t&7)
                unsigned lo = f2bf(v[0] + bias) | (f2bf(v[1] + bias) << 16);
                unsigned hi = f2bf(v[2] + bias) | (f2bf(v[3] + bias) << 16);
                uint2 pk; pk.x = lo; pk.y = hi;
                int itv = sb >> 6, sub = (d >> 4) * 2 + ((sb >> 5) & 1);
                size_t off = ((bh * 16 + itv) * 8 + sub) * 512
                           + (((sb >> 3) & 3) * 16 + (d & 15)) * 8 + (sb & 7);
                *(uint2*)&vb[off] = pk;
            } else if (type == 1) {
                // kb blocked: elem (bh,t,d): it=t>>6, sub=((t>>4)&3)*2+(d>>5),
                //   off = ((bh*16+it)*8+sub)*512 + (((d>>3)&3)*16 + (t&15))*8 + (d&7)
#pragma unroll
                for (int r = 0; r < 4; ++r) {
                    int t = sb + r;
                    int itk = t >> 6, sub = ((t >> 4) & 3) * 2 + (d >> 5);
                    size_t off = ((bh * 16 + itk) * 8 + sub) * 512
                               + (((d >> 3) & 3) * 16 + (t & 15)) * 8 + (d & 7);
                    kb[off] = (ushort_t)f2bf(v[r] + bias);
                }
            } else {
#pragma unroll
                for (int r = 0; r < 4; ++r)
                    q_buf[(bh * SEQ + sb + r) * DHEAD + d] =
                        (ushort_t)f2bf((v[r] + bias) * ATTN_SCALE);
            }
        }
    }
}

// ---------------------------------------------------------------------------
// Kernel 2: MFMA flash attention; blocked contiguous K/V staging; dbuf;
//   unnormalized-exp softmax; S^T trick; L via ones-MFMA.  Epilogue writes
//   resb in out_gemm's blocked order.  Grid: (bh=128, qtile=8); 48 KB LDS.
// ---------------------------------------------------------------------------
__global__ __launch_bounds__(256) void attn_kernel(
    const ushort_t* __restrict__ q_buf, const ushort_t* __restrict__ kb,
    const ushort_t* __restrict__ vb, ushort_t* __restrict__ resb)
{
    __shared__ alignas(16) ushort_t Kf[2][8 * 512];   // ping-pong, 16 KB
    __shared__ alignas(16) ushort_t Vf[2][8 * 512];   // ping-pong, 16 KB
    __shared__ alignas(16) ushort_t Pf[8 * 1024];     // 16 KB: 4 waves x 2 groups

    const int tid  = threadIdx.x;
    const int w    = tid >> 6;
    const int lane = tid & 63;
    const int quad = lane >> 4;
    const int col  = lane & 15;

    const int bhid = blockIdx.x;          // 0..127
    const int b = bhid >> 3, h = bhid & 7;
    const int q0 = blockIdx.y * 128;
    const size_t bh = (size_t)b * HEADS + h;

    // Q B-frags for 2 groups (pre-scaled by ATTN_SCALE in qkv_gemm)
    const ushort_t* qp = q_buf + ((bh * SEQ) + q0 + w * 32 + col) * DHEAD + quad * 8;
    short8 qf0[2], qf1[2];
    qf0[0] = *(const short8*)(qp);
    qf1[0] = *(const short8*)(qp + 32);
    qf0[1] = *(const short8*)(qp + 16 * DHEAD);
    qf1[1] = *(const short8*)(qp + 16 * DHEAD + 32);

    short8 ones;
#pragma unroll
    for (int i = 0; i < 8; ++i) ones[i] = (short)0x3F80;

    f32x4 O[2][4];
#pragma unroll
    for (int g = 0; g < 2; ++g)
#pragma unroll
        for (int i = 0; i < 4; ++i) O[g][i] = (f32x4){0.f, 0.f, 0.f, 0.f};
    f32x4 L[2];
    L[0] = (f32x4){0.f, 0.f, 0.f, 0.f};
    L[1] = (f32x4){0.f, 0.f, 0.f, 0.f};

    // blocked contiguous staging pointers (wave w stages subs w*2+{0,1})
    const ushort_t* kaB = kb + (size_t)bh * 65536 + (w * 2) * 512 + lane * 8;
    const ushort_t* vaB = vb + (size_t)bh * 65536 + (w * 2) * 512 + lane * 8;

    // P write offset: off = (t16>>1)*512 + ((t16*2+(quad>>1))&3)*128 + col*8 + (quad&1)*4
    const int poff_base = col * 8 + (quad & 1) * 4;
    const int qh = quad >> 1;

    async16(kaB,       &Kf[0][(w * 2 + 0) * 512]);
    async16(kaB + 512, &Kf[0][(w * 2 + 1) * 512]);
    async16(vaB,       &Vf[0][(w * 2 + 0) * 512]);
    async16(vaB + 512, &Vf[0][(w * 2 + 1) * 512]);
    kaB += 4096;
    vaB += 4096;

    for (int it = 0; it < 16; ++it) {
        const int cur = it & 1;
        const ushort_t* kc = Kf[cur];
        const ushort_t* vc = Vf[cur];
        __syncthreads();   // buf[cur] staged; prior readers of buf[cur^1] done
        if (it < 15) {
            async16(kaB,       &Kf[cur ^ 1][(w * 2 + 0) * 512]);
            async16(kaB + 512, &Kf[cur ^ 1][(w * 2 + 1) * 512]);
            async16(vaB,       &Vf[cur ^ 1][(w * 2 + 0) * 512]);
            async16(vaB + 512, &Vf[cur ^ 1][(w * 2 + 1) * 512]);
            kaB += 4096;
            vaB += 4096;
        }

        // ---- S^T = K Q^T; K frags shared by both groups ----
        f32x4 S[2][4];
#pragma unroll
        for (int t16 = 0; t16 < 4; ++t16) {
            const short8 k0 = *(const short8*)&kc[(t16 * 2 + 0) * 512 + lane * 8];
            const short8 k1 = *(const short8*)&kc[(t16 * 2 + 1) * 512 + lane * 8];
#pragma unroll
            for (int g = 0; g < 2; ++g) {
                f32x4 a = (f32x4){0.f, 0.f, 0.f, 0.f};
                a = __builtin_amdgcn_mfma_f32_16x16x32_bf16(k0, qf0[g], a, 0, 0, 0);
                a = __builtin_amdgcn_mfma_f32_16x16x32_bf16(k1, qf1[g], a, 0, 0, 0);
                S[g][t16] = a;
            }
        }

        // ---- P = exp(S) -> A-layout LDS (1 ds_write_b64 per (g,t16)) ----
#pragma unroll
        for (int g = 0; g < 2; ++g) {
            ushort_t* pg = &Pf[(w * 2 + g) * 1024];
#pragma unroll
            for (int t16 = 0; t16 < 4; ++t16) {
                uint2 pk;
                pk.x = bfu_trunc(__expf(S[g][t16][0])) | (bfu_trunc(__expf(S[g][t16][1])) << 16);
                pk.y = bfu_trunc(__expf(S[g][t16][2])) | (bfu_trunc(__expf(S[g][t16][3])) << 16);
                int off = (t16 >> 1) * 512 + (((t16 * 2) + qh) & 3) * 128 + poff_base;
                *(uint2*)&pg[off] = pk;
            }
        }
        short8 pf[2][2];
#pragma unroll
        for (int g = 0; g < 2; ++g) {
            const ushort_t* pg = &Pf[(w * 2 + g) * 1024];
            pf[g][0] = *(const short8*)&pg[lane * 8];
            pf[g][1] = *(const short8*)&pg[512 + lane * 8];
        }

        // ---- O += P V ; V frags shared by both groups ----
#pragma unroll
        for (int d16 = 0; d16 < 4; ++d16) {
            const short8 v0 = *(const short8*)&vc[(d16 * 2 + 0) * 512 + lane * 8];
            const short8 v1 = *(const short8*)&vc[(d16 * 2 + 1) * 512 + lane * 8];
#pragma unroll
            for (int g = 0; g < 2; ++g) {
                O[g][d16] = __builtin_amdgcn_mfma_f32_16x16x32_bf16(pf[g][0], v0, O[g][d16], 0, 0, 0);
                O[g][d16] = __builtin_amdgcn_mfma_f32_16x16x32_bf16(pf[g][1], v1, O[g][d16], 0, 0, 0);
            }
        }
#pragma unroll
        for (int g = 0; g < 2; ++g) {
            L[g] = __builtin_amdgcn_mfma_f32_16x16x32_bf16(pf[g][0], ones, L[g], 0, 0, 0);
            L[g] = __builtin_amdgcn_mfma_f32_16x16x32_bf16(pf[g][1], ones, L[g], 0, 0, 0);
        }
    }

    // ---- epilogue: O / L -> resb in out_gemm's blocked order ----
    //   elem (m = b*1024 + qg, k = h*64 + d16*16 + col):
    //   mt = b*8 + q0>>7 (q0 128-aligned), m16 = w*2+g, mcol = quad*4+r
    //   it = h*2 + (d16>>1), kq = (d16&1)*2 + (col>>3), kj = col&7
    const int mt = b * 8 + (q0 >> 7);
#pragma unroll
    for (int g = 0; g < 2; ++g) {
        const int m16 = w * 2 + g;
#pragma unroll
        for (int r = 0; r < 4; ++r) {
            float inv = 1.f / L[g][r];
            const int mcol = quad * 4 + r;
#pragma unroll
            for (int d16 = 0; d16 < 4; ++d16) {
                int itk = h * 2 + (d16 >> 1);
                int kq = (d16 & 1) * 2 + (col >> 3);
                size_t off = ((size_t)(mt * 16 + itk) * 8 + m16) * 512
                           + (kq * 16 + mcol) * 8 + (col & 7);
                resb[off] = (ushort_t)f2bf(O[g][d16][r] * inv);
            }
        }
    }
}

// ---------------------------------------------------------------------------
// Kernel 3: out GEMM (MFMA), BK=32 dbuf, blocked staging, XCD swizzle.
//   out[b][n][s] = res[m][:].Wo[:,n] + bo[n] + x.  Grid: (4, 128); 32 KB LDS.
// ---------------------------------------------------------------------------
__global__ __launch_bounds__(256) void out_gemm_kernel(
    const ushort_t* __restrict__ resb, const ushort_t* __restrict__ WoTb,
    const float* __restrict__ bo, const float* __restrict__ x,
    float* __restrict__ out)
{
    __shared__ alignas(16) ushort_t Asub[2][8 * 512];
    __shared__ alignas(16) ushort_t Bsub[2][8 * 512];

    const int tid = threadIdx.x, w = tid >> 6, lane = tid & 63;
    const int quad = lane >> 4, col = lane & 15;
    const int wm = w >> 1, wn = w & 1;

    const int lin = blockIdx.x + 4 * blockIdx.y;    // 0..511
    const int xcd = lin & 7;
    const int rr  = lin >> 3;
    const int n0  = (rr & 3) * 128;
    const int m0  = ((rr >> 2) * 8 + xcd) * 128;

    f32x4 acc[4][4];
#pragma unroll
    for (int i = 0; i < 4; ++i)
#pragma unroll
        for (int j = 0; j < 4; ++j) acc[i][j] = (f32x4){0.f, 0.f, 0.f, 0.f};

    const ushort_t* Ab = resb + (size_t)(m0 >> 7) * 65536 + (w * 2) * 512 + lane * 8;
    const ushort_t* Bb = WoTb + (size_t)(n0 >> 7) * 65536 + (w * 2) * 512 + lane * 8;

#define OUT_STAGE(buf, it)                                        \
    do {                                                          \
        async16(Ab + (it) * 4096,       &Asub[buf][(w * 2 + 0) * 512]); \
        async16(Ab + (it) * 4096 + 512, &Asub[buf][(w * 2 + 1) * 512]); \
        async16(Bb + (it) * 4096,       &Bsub[buf][(w * 2 + 0) * 512]); \
        async16(Bb + (it) * 4096 + 512, &Bsub[buf][(w * 2 + 1) * 512]); \
    } while (0)

    OUT_STAGE(0, 0);
    for (int it = 0; it < 16; ++it) {
        const int cur = it & 1;
        __syncthreads();
        if (it < 15) OUT_STAGE(cur ^ 1, it + 1);

        short8 af[4], bfr[4];
#pragma unroll
        for (int i = 0; i < 4; ++i) af[i]  = *(const short8*)&Asub[cur][(wm * 4 + i) * 512 + lane * 8];
#pragma unroll
        for (int j = 0; j < 4; ++j) bfr[j] = *(const short8*)&Bsub[cur][(wn * 4 + j) * 512 + lane * 8];
#pragma unroll
        for (int i = 0; i < 4; ++i)
#pragma unroll
            for (int j = 0; j < 4; ++j)
                acc[i][j] = __builtin_amdgcn_mfma_f32_16x16x32_bf16(af[i], bfr[j], acc[i][j], 0, 0, 0);
    }
#undef OUT_STAGE

    const int b = m0 >> 10, s0 = m0 & 1023;
#pragma unroll
    for (int j = 0; j < 4; ++j) {
        int n = n0 + wn * 64 + j * 16 + col;
        float bias = bo[n];
#pragma unroll
        for (int i = 0; i < 4; ++i) {
            int sb = s0 + wm * 64 + i * 16 + quad * 4;
            size_t o = ((size_t)b * CDIM + n) * SEQ + sb;
            float4 xr = *(const float4*)&x[o];
            f32x4 v = acc[i][j];
            float4 ov;
            ov.x = v[0] + bias + xr.x;
            ov.y = v[1] + bias + xr.y;
            ov.z = v[2] + bias + xr.z;
            ov.w = v[3] + bias + xr.w;
            *(float4*)&out[o] = ov;
        }
    }
}

// ---------------------------------------------------------------------------
extern "C" void kernel_launch(void* const* d_in, const int* in_sizes, int n_in,
                              void* d_out, int out_size, void* d_ws, size_t ws_size,
                              hipStream_t stream) {
    const float* x  = (const float*)d_in[0];   // (16, 512, 32, 32) fp32
    const float* Wp = (const float*)d_in[1];   // (512, 1536) fp32
    const float* bp = (const float*)d_in[2];   // (1536,) fp32
    const float* Wo = (const float*)d_in[3];   // (512, 512) fp32
    const float* bo = (const float*)d_in[4];   // (512,) fp32
    float* out = (float*)d_out;                // (16, 512, 32, 32) fp32

    // ws layout (ushort units), ~86 MB
    ushort_t* xtb   = (ushort_t*)d_ws;               // blocked [mt][it][sub][lane][8]
    ushort_t* WpTb  = xtb   + (size_t)8388608;
    ushort_t* WoTb  = WpTb  + (size_t)786432;
    ushort_t* q_buf = WoTb  + (size_t)262144;        // row-major [bh][s][d]
    ushort_t* kb    = q_buf + (size_t)8388608;       // attn-blocked
    ushort_t* vb    = kb    + (size_t)8388608;       // attn-blocked
    ushort_t* resb  = vb    + (size_t)8388608;       // out_gemm-blocked

    blockify_kernel<<<dim3(16, 8, 16), 256, 0, stream>>>(x,  xtb,  1024);
    blockify_kernel<<<dim3(24, 8, 1),  256, 0, stream>>>(Wp, WpTb, 1536);
    blockify_kernel<<<dim3(8, 8, 1),   256, 0, stream>>>(Wo, WoTb, 512);
    qkv_gemm_kernel<<<dim3(12, 128), 256, 0, stream>>>(xtb, WpTb, bp, q_buf, kb, vb);
    attn_kernel<<<dim3(128, 8), 256, 0, stream>>>(q_buf, kb, vb, resb);
    out_gemm_kernel<<<dim3(4, 128), 256, 0, stream>>>(resb, WoTb, bo, x, out);
}

// Round 13
// 201.410 us; speedup vs baseline: 1.1874x; 1.0068x over previous
//
#include <hip/hip_runtime.h>
#include <hip/hip_bf16.h>

#define BATCH 16
#define CDIM  512
#define SEQ   1024
#define HEADS 8
#define DHEAD 64
#define N3    1536      // 3 * HEADS * DHEAD
// q pre-scale: dk^-0.5 * log2(e), so attn uses exp2 directly (softmax-invariant)
#define QSCALE 0.18033688011112042f

typedef unsigned short ushort_t;
typedef __attribute__((ext_vector_type(8))) short short8;   // 8 bf16 (4 VGPRs)
typedef __attribute__((ext_vector_type(4))) float f32x4;

// fp32 -> bf16 bits, round-to-nearest-even
__device__ __forceinline__ unsigned f2bf(float f) {
    unsigned u = __float_as_uint(f);
    u += 0x7fffu + ((u >> 16) & 1u);
    return u >> 16;
}
// 2^x via v_exp_f32 (quarter-rate transcendental; inputs are normal-range)
__device__ __forceinline__ float fast_exp2(float x) {
    float r;
    asm("v_exp_f32 %0, %1" : "=v"(r) : "v"(x));
    return r;
}
// pack trunc-bf16(lo), trunc-bf16(hi) -> one u32 via v_perm_b32 (1 VALU op)
__device__ __forceinline__ unsigned pack_bf16_trunc(float lo, float hi) {
    return __builtin_amdgcn_perm(__float_as_uint(hi), __float_as_uint(lo), 0x07060302u);
}
// async global->LDS, 16B/lane; per-lane ptr pre-offset by lane*16B so each
// wave covers 1 KB CONTIGUOUS global memory (one transaction, not 64).
__device__ __forceinline__ void async16(const void* g, void* l) {
    __builtin_amdgcn_global_load_lds(
        (const __attribute__((address_space(1))) unsigned int*)g,
        (__attribute__((address_space(3))) unsigned int*)l, 16, 0, 0);
}

// ---------------------------------------------------------------------------
// Blocked fragment-order layout for GEMM staging (all staged operands):
//   element (m, k):  mt=m>>7, mr=m&127, m16=mr>>4, col=mr&15,
//                    it=k>>5, q=(k>>3)&3, j=k&7
//   off = ((mt*16+it)*8 + m16)*512 + (q*16+col)*8 + j
// One (mt,it,m16) chunk = 512 ushorts = 1 KB contiguous = one async16/wave.
// ---------------------------------------------------------------------------

// Kernel 0: transpose + bf16 + blockify.  in[512][C] fp32 (k-major), m = z*C+c.
//   Grid: (C/64, 8, batches); 256 threads.
__global__ __launch_bounds__(256) void blockify_kernel(
    const float* __restrict__ in, ushort_t* __restrict__ out, int C)
{
    __shared__ float t[64][65];
    const int k0 = blockIdx.y * 64, c0 = blockIdx.x * 64;
    const float* inb = in + (size_t)blockIdx.z * 512 * C;
    const int tid = threadIdx.x;
#pragma unroll
    for (int i = 0; i < 16; ++i) {
        int idx = tid + i * 256;
        int r = idx >> 6, c = idx & 63;
        t[r][c] = inb[(size_t)(k0 + r) * C + c0 + c];
    }
    __syncthreads();
    const size_t mbase = (size_t)blockIdx.z * C + c0;
    const int ml = tid & 63;
#pragma unroll
    for (int i = 0; i < 2; ++i) {
        int oct = (tid >> 6) + i * 4;          // k-octet 0..7
        size_t m = mbase + ml;
        int mt = (int)(m >> 7), mr = (int)(m & 127);
        int m16 = mr >> 4, col = mr & 15;
        int k = k0 + oct * 8;
        int it = k >> 5, q = (k >> 3) & 3;
        uint4 pk;
        pk.x = f2bf(t[oct * 8 + 0][ml]) | (f2bf(t[oct * 8 + 1][ml]) << 16);
        pk.y = f2bf(t[oct * 8 + 2][ml]) | (f2bf(t[oct * 8 + 3][ml]) << 16);
        pk.z = f2bf(t[oct * 8 + 4][ml]) | (f2bf(t[oct * 8 + 5][ml]) << 16);
        pk.w = f2bf(t[oct * 8 + 6][ml]) | (f2bf(t[oct * 8 + 7][ml]) << 16);
        size_t off = ((size_t)(mt * 16 + it) * 8 + m16) * 512 + (q * 16 + col) * 8;
        *(uint4*)&out[off] = pk;
    }
}

// ---------------------------------------------------------------------------
// Kernel 1: QKV GEMM (MFMA), BK=32 dbuf, blocked contiguous staging, XCD
//   swizzle.  Epilogue: q row-major pre-scaled by QSCALE; k/v in attn's
//   blocked fragment order.  Grid: (12, 128); 256 thr; 32 KB LDS.
// ---------------------------------------------------------------------------
__global__ __launch_bounds__(256) void qkv_gemm_kernel(
    const ushort_t* __restrict__ xtb, const ushort_t* __restrict__ WpTb,
    const float* __restrict__ bp,
    ushort_t* __restrict__ q_buf, ushort_t* __restrict__ kb,
    ushort_t* __restrict__ vb)
{
    __shared__ alignas(16) ushort_t Asub[2][8 * 512];   // 2 x 8 KB
    __shared__ alignas(16) ushort_t Bsub[2][8 * 512];   // 2 x 8 KB

    const int tid = threadIdx.x, w = tid >> 6, lane = tid & 63;
    const int quad = lane >> 4, col = lane & 15;
    const int wm = w >> 1, wn = w & 1;

    // XCD swizzle: all 12 n-tiles of one m-tile on one XCD
    const int lin = blockIdx.x + 12 * blockIdx.y;   // 0..1535
    const int xcd = lin & 7;
    const int rr  = lin >> 3;
    const int n0  = (rr % 12) * 128;
    const int m0  = ((rr / 12) * 8 + xcd) * 128;

    f32x4 acc[4][4];
#pragma unroll
    for (int i = 0; i < 4; ++i)
#pragma unroll
        for (int j = 0; j < 4; ++j) acc[i][j] = (f32x4){0.f, 0.f, 0.f, 0.f};

    const ushort_t* Ab = xtb  + (size_t)(m0 >> 7) * 65536 + (w * 2) * 512 + lane * 8;
    const ushort_t* Bb = WpTb + (size_t)(n0 >> 7) * 65536 + (w * 2) * 512 + lane * 8;

#define QKV_STAGE(buf, it)                                        \
    do {                                                          \
        async16(Ab + (it) * 4096,       &Asub[buf][(w * 2 + 0) * 512]); \
        async16(Ab + (it) * 4096 + 512, &Asub[buf][(w * 2 + 1) * 512]); \
        async16(Bb + (it) * 4096,       &Bsub[buf][(w * 2 + 0) * 512]); \
        async16(Bb + (it) * 4096 + 512, &Bsub[buf][(w * 2 + 1) * 512]); \
    } while (0)

    QKV_STAGE(0, 0);
    for (int it = 0; it < 16; ++it) {
        const int cur = it & 1;
        __syncthreads();                 // buf[cur] staged; buf[cur^1] readers done
        if (it < 15) QKV_STAGE(cur ^ 1, it + 1);

        short8 af[4], bfr[4];
#pragma unroll
        for (int i = 0; i < 4; ++i) af[i]  = *(const short8*)&Asub[cur][(wm * 4 + i) * 512 + lane * 8];
#pragma unroll
        for (int j = 0; j < 4; ++j) bfr[j] = *(const short8*)&Bsub[cur][(wn * 4 + j) * 512 + lane * 8];
#pragma unroll
        for (int i = 0; i < 4; ++i)
#pragma unroll
            for (int j = 0; j < 4; ++j)
                acc[i][j] = __builtin_amdgcn_mfma_f32_16x16x32_bf16(af[i], bfr[j], acc[i][j], 0, 0, 0);
    }
#undef QKV_STAGE

    // ---- epilogue: split q/k/v; q pre-scaled by QSCALE ----
    const int b = m0 >> 10, s0 = m0 & 1023;
    const size_t b8 = (size_t)b * HEADS;
#pragma unroll
    for (int j = 0; j < 4; ++j) {
        int nb = n0 + wn * 64 + j * 16;               // frag n base (wave-uniform)
        int h = nb / 192, rem = nb % 192;
        int type = rem >> 6, dbase = rem & 63;        // uniform per frag
        float bias = bp[nb + col];
        size_t bh = b8 + h;
        int d = dbase + col;
#pragma unroll
        for (int i = 0; i < 4; ++i) {
            int sb = s0 + wm * 64 + i * 16 + quad * 4;    // s for r=0
            f32x4 v = acc[i][j];
            if (type == 2) {
                // vb blocked: elem (bh,d,t): it=t>>6, sub=(d>>4)*2+((t>>5)&1)
                unsigned lo = f2bf(v[0] + bias) | (f2bf(v[1] + bias) << 16);
                unsigned hi = f2bf(v[2] + bias) | (f2bf(v[3] + bias) << 16);
                uint2 pk; pk.x = lo; pk.y = hi;
                int itv = sb >> 6, sub = (d >> 4) * 2 + ((sb >> 5) & 1);
                size_t off = ((bh * 16 + itv) * 8 + sub) * 512
                           + (((sb >> 3) & 3) * 16 + (d & 15)) * 8 + (sb & 7);
                *(uint2*)&vb[off] = pk;
            } else if (type == 1) {
                // kb blocked: elem (bh,t,d): it=t>>6, sub=((t>>4)&3)*2+(d>>5)
#pragma unroll
                for (int r = 0; r < 4; ++r) {
                    int t = sb + r;
                    int itk = t >> 6, sub = ((t >> 4) & 3) * 2 + (d >> 5);
                    size_t off = ((bh * 16 + itk) * 8 + sub) * 512
                               + (((d >> 3) & 3) * 16 + (t & 15)) * 8 + (d & 7);
                    kb[off] = (ushort_t)f2bf(v[r] + bias);
                }
            } else {
#pragma unroll
                for (int r = 0; r < 4; ++r)
                    q_buf[(bh * SEQ + sb + r) * DHEAD + d] =
                        (ushort_t)f2bf((v[r] + bias) * QSCALE);
            }
        }
    }
}

// ---------------------------------------------------------------------------
// Kernel 2: MFMA flash attention; blocked contiguous K/V staging; dbuf;
//   unnormalized softmax via exp2 (q pre-scaled by log2e); S^T trick;
//   per-wave single P buffer (write g -> read g -> overwrite by g+1; same-wave
//   DS ops are in-order).  40 KB LDS -> 4 blocks/CU, grid 1024 = exact fit.
//   Grid: (bh=128, qtile=8); 256 threads.
// ---------------------------------------------------------------------------
__global__ __launch_bounds__(256) void attn_kernel(
    const ushort_t* __restrict__ q_buf, const ushort_t* __restrict__ kb,
    const ushort_t* __restrict__ vb, ushort_t* __restrict__ resb)
{
    __shared__ alignas(16) ushort_t Kf[2][8 * 512];   // ping-pong, 16 KB
    __shared__ alignas(16) ushort_t Vf[2][8 * 512];   // ping-pong, 16 KB
    __shared__ alignas(16) ushort_t Pf[4 * 1024];     // 8 KB: 1 per wave, shared by groups

    const int tid  = threadIdx.x;
    const int w    = tid >> 6;
    const int lane = tid & 63;
    const int quad = lane >> 4;
    const int col  = lane & 15;

    const int bhid = blockIdx.x;          // 0..127
    const int b = bhid >> 3, h = bhid & 7;
    const int q0 = blockIdx.y * 128;
    const size_t bh = (size_t)b * HEADS + h;

    // Q B-frags for 2 groups (pre-scaled by QSCALE in qkv_gemm)
    const ushort_t* qp = q_buf + ((bh * SEQ) + q0 + w * 32 + col) * DHEAD + quad * 8;
    short8 qf0[2], qf1[2];
    qf0[0] = *(const short8*)(qp);
    qf1[0] = *(const short8*)(qp + 32);
    qf0[1] = *(const short8*)(qp + 16 * DHEAD);
    qf1[1] = *(const short8*)(qp + 16 * DHEAD + 32);

    short8 ones;
#pragma unroll
    for (int i = 0; i < 8; ++i) ones[i] = (short)0x3F80;

    f32x4 O[2][4];
#pragma unroll
    for (int g = 0; g < 2; ++g)
#pragma unroll
        for (int i = 0; i < 4; ++i) O[g][i] = (f32x4){0.f, 0.f, 0.f, 0.f};
    f32x4 L[2];
    L[0] = (f32x4){0.f, 0.f, 0.f, 0.f};
    L[1] = (f32x4){0.f, 0.f, 0.f, 0.f};

    // blocked contiguous staging pointers (wave w stages subs w*2+{0,1})
    const ushort_t* kaB = kb + (size_t)bh * 65536 + (w * 2) * 512 + lane * 8;
    const ushort_t* vaB = vb + (size_t)bh * 65536 + (w * 2) * 512 + lane * 8;

    // P write offset: off = (t16>>1)*512 + ((t16*2+(quad>>1))&3)*128 + col*8 + (quad&1)*4
    const int poff_base = col * 8 + (quad & 1) * 4;
    const int qh = quad >> 1;
    ushort_t* pg = &Pf[w * 1024];

    async16(kaB,       &Kf[0][(w * 2 + 0) * 512]);
    async16(kaB + 512, &Kf[0][(w * 2 + 1) * 512]);
    async16(vaB,       &Vf[0][(w * 2 + 0) * 512]);
    async16(vaB + 512, &Vf[0][(w * 2 + 1) * 512]);
    kaB += 4096;
    vaB += 4096;

    for (int it = 0; it < 16; ++it) {
        const int cur = it & 1;
        const ushort_t* kc = Kf[cur];
        const ushort_t* vc = Vf[cur];
        __syncthreads();   // buf[cur] staged; prior readers of buf[cur^1] done
        if (it < 15) {
            async16(kaB,       &Kf[cur ^ 1][(w * 2 + 0) * 512]);
            async16(kaB + 512, &Kf[cur ^ 1][(w * 2 + 1) * 512]);
            async16(vaB,       &Vf[cur ^ 1][(w * 2 + 0) * 512]);
            async16(vaB + 512, &Vf[cur ^ 1][(w * 2 + 1) * 512]);
            kaB += 4096;
            vaB += 4096;
        }

        // ---- S^T = K Q^T; K frags shared by both groups ----
        f32x4 S[2][4];
#pragma unroll
        for (int t16 = 0; t16 < 4; ++t16) {
            const short8 k0 = *(const short8*)&kc[(t16 * 2 + 0) * 512 + lane * 8];
            const short8 k1 = *(const short8*)&kc[(t16 * 2 + 1) * 512 + lane * 8];
#pragma unroll
            for (int g = 0; g < 2; ++g) {
                f32x4 a = (f32x4){0.f, 0.f, 0.f, 0.f};
                a = __builtin_amdgcn_mfma_f32_16x16x32_bf16(k0, qf0[g], a, 0, 0, 0);
                a = __builtin_amdgcn_mfma_f32_16x16x32_bf16(k1, qf1[g], a, 0, 0, 0);
                S[g][t16] = a;
            }
        }

        // ---- P = exp2(S) -> per-wave LDS, one group at a time ----
        short8 pf[2][2];
#pragma unroll
        for (int g = 0; g < 2; ++g) {
#pragma unroll
            for (int t16 = 0; t16 < 4; ++t16) {
                uint2 pk;
                pk.x = pack_bf16_trunc(fast_exp2(S[g][t16][0]), fast_exp2(S[g][t16][1]));
                pk.y = pack_bf16_trunc(fast_exp2(S[g][t16][2]), fast_exp2(S[g][t16][3]));
                int off = (t16 >> 1) * 512 + (((t16 * 2) + qh) & 3) * 128 + poff_base;
                *(uint2*)&pg[off] = pk;
            }
            // same-wave in-order DS: these reads complete before g+1's writes
            pf[g][0] = *(const short8*)&pg[lane * 8];
            pf[g][1] = *(const short8*)&pg[512 + lane * 8];
        }

        // ---- O += P V ; V frags shared by both groups ----
#pragma unroll
        for (int d16 = 0; d16 < 4; ++d16) {
            const short8 v0 = *(const short8*)&vc[(d16 * 2 + 0) * 512 + lane * 8];
            const short8 v1 = *(const short8*)&vc[(d16 * 2 + 1) * 512 + lane * 8];
#pragma unroll
            for (int g = 0; g < 2; ++g) {
                O[g][d16] = __builtin_amdgcn_mfma_f32_16x16x32_bf16(pf[g][0], v0, O[g][d16], 0, 0, 0);
                O[g][d16] = __builtin_amdgcn_mfma_f32_16x16x32_bf16(pf[g][1], v1, O[g][d16], 0, 0, 0);
            }
        }
#pragma unroll
        for (int g = 0; g < 2; ++g) {
            L[g] = __builtin_amdgcn_mfma_f32_16x16x32_bf16(pf[g][0], ones, L[g], 0, 0, 0);
            L[g] = __builtin_amdgcn_mfma_f32_16x16x32_bf16(pf[g][1], ones, L[g], 0, 0, 0);
        }
    }

    // ---- epilogue: O / L -> resb in out_gemm's blocked order ----
    const int mt = b * 8 + (q0 >> 7);
#pragma unroll
    for (int g = 0; g < 2; ++g) {
        const int m16 = w * 2 + g;
#pragma unroll
        for (int r = 0; r < 4; ++r) {
            float inv = 1.f / L[g][r];
            const int mcol = quad * 4 + r;
#pragma unroll
            for (int d16 = 0; d16 < 4; ++d16) {
                int itk = h * 2 + (d16 >> 1);
                int kq = (d16 & 1) * 2 + (col >> 3);
                size_t off = ((size_t)(mt * 16 + itk) * 8 + m16) * 512
                           + (kq * 16 + mcol) * 8 + (col & 7);
                resb[off] = (ushort_t)f2bf(O[g][d16][r] * inv);
            }
        }
    }
}

// ---------------------------------------------------------------------------
// Kernel 3: out GEMM (MFMA), BK=32 dbuf, blocked staging, XCD swizzle.
//   out[b][n][s] = res[m][:].Wo[:,n] + bo[n] + x.  Grid: (4, 128); 32 KB LDS.
// ---------------------------------------------------------------------------
__global__ __launch_bounds__(256) void out_gemm_kernel(
    const ushort_t* __restrict__ resb, const ushort_t* __restrict__ WoTb,
    const float* __restrict__ bo, const float* __restrict__ x,
    float* __restrict__ out)
{
    __shared__ alignas(16) ushort_t Asub[2][8 * 512];
    __shared__ alignas(16) ushort_t Bsub[2][8 * 512];

    const int tid = threadIdx.x, w = tid >> 6, lane = tid & 63;
    const int quad = lane >> 4, col = lane & 15;
    const int wm = w >> 1, wn = w & 1;

    const int lin = blockIdx.x + 4 * blockIdx.y;    // 0..511
    const int xcd = lin & 7;
    const int rr  = lin >> 3;
    const int n0  = (rr & 3) * 128;
    const int m0  = ((rr >> 2) * 8 + xcd) * 128;

    f32x4 acc[4][4];
#pragma unroll
    for (int i = 0; i < 4; ++i)
#pragma unroll
        for (int j = 0; j < 4; ++j) acc[i][j] = (f32x4){0.f, 0.f, 0.f, 0.f};

    const ushort_t* Ab = resb + (size_t)(m0 >> 7) * 65536 + (w * 2) * 512 + lane * 8;
    const ushort_t* Bb = WoTb + (size_t)(n0 >> 7) * 65536 + (w * 2) * 512 + lane * 8;

#define OUT_STAGE(buf, it)                                        \
    do {                                                          \
        async16(Ab + (it) * 4096,       &Asub[buf][(w * 2 + 0) * 512]); \
        async16(Ab + (it) * 4096 + 512, &Asub[buf][(w * 2 + 1) * 512]); \
        async16(Bb + (it) * 4096,       &Bsub[buf][(w * 2 + 0) * 512]); \
        async16(Bb + (it) * 4096 + 512, &Bsub[buf][(w * 2 + 1) * 512]); \
    } while (0)

    OUT_STAGE(0, 0);
    for (int it = 0; it < 16; ++it) {
        const int cur = it & 1;
        __syncthreads();
        if (it < 15) OUT_STAGE(cur ^ 1, it + 1);

        short8 af[4], bfr[4];
#pragma unroll
        for (int i = 0; i < 4; ++i) af[i]  = *(const short8*)&Asub[cur][(wm * 4 + i) * 512 + lane * 8];
#pragma unroll
        for (int j = 0; j < 4; ++j) bfr[j] = *(const short8*)&Bsub[cur][(wn * 4 + j) * 512 + lane * 8];
#pragma unroll
        for (int i = 0; i < 4; ++i)
#pragma unroll
            for (int j = 0; j < 4; ++j)
                acc[i][j] = __builtin_amdgcn_mfma_f32_16x16x32_bf16(af[i], bfr[j], acc[i][j], 0, 0, 0);
    }
#undef OUT_STAGE

    const int b = m0 >> 10, s0 = m0 & 1023;
#pragma unroll
    for (int j = 0; j < 4; ++j) {
        int n = n0 + wn * 64 + j * 16 + col;
        float bias = bo[n];
#pragma unroll
        for (int i = 0; i < 4; ++i) {
            int sb = s0 + wm * 64 + i * 16 + quad * 4;
            size_t o = ((size_t)b * CDIM + n) * SEQ + sb;
            float4 xr = *(const float4*)&x[o];
            f32x4 v = acc[i][j];
            float4 ov;
            ov.x = v[0] + bias + xr.x;
            ov.y = v[1] + bias + xr.y;
            ov.z = v[2] + bias + xr.z;
            ov.w = v[3] + bias + xr.w;
            *(float4*)&out[o] = ov;
        }
    }
}

// ---------------------------------------------------------------------------
extern "C" void kernel_launch(void* const* d_in, const int* in_sizes, int n_in,
                              void* d_out, int out_size, void* d_ws, size_t ws_size,
                              hipStream_t stream) {
    const float* x  = (const float*)d_in[0];   // (16, 512, 32, 32) fp32
    const float* Wp = (const float*)d_in[1];   // (512, 1536) fp32
    const float* bp = (const float*)d_in[2];   // (1536,) fp32
    const float* Wo = (const float*)d_in[3];   // (512, 512) fp32
    const float* bo = (const float*)d_in[4];   // (512,) fp32
    float* out = (float*)d_out;                // (16, 512, 32, 32) fp32

    // ws layout (ushort units), ~86 MB
    ushort_t* xtb   = (ushort_t*)d_ws;               // blocked [mt][it][sub][lane][8]
    ushort_t* WpTb  = xtb   + (size_t)8388608;
    ushort_t* WoTb  = WpTb  + (size_t)786432;
    ushort_t* q_buf = WoTb  + (size_t)262144;        // row-major [bh][s][d]
    ushort_t* kb    = q_buf + (size_t)8388608;       // attn-blocked
    ushort_t* vb    = kb    + (size_t)8388608;       // attn-blocked
    ushort_t* resb  = vb    + (size_t)8388608;       // out_gemm-blocked

    blockify_kernel<<<dim3(16, 8, 16), 256, 0, stream>>>(x,  xtb,  1024);
    blockify_kernel<<<dim3(24, 8, 1),  256, 0, stream>>>(Wp, WpTb, 1536);
    blockify_kernel<<<dim3(8, 8, 1),   256, 0, stream>>>(Wo, WoTb, 512);
    qkv_gemm_kernel<<<dim3(12, 128), 256, 0, stream>>>(xtb, WpTb, bp, q_buf, kb, vb);
    attn_kernel<<<dim3(128, 8), 256, 0, stream>>>(q_buf, kb, vb, resb);
    out_gemm_kernel<<<dim3(4, 128), 256, 0, stream>>>(resb, WoTb, bo, x, out);
}